// Round 1
// baseline (4214.698 us; speedup 1.0000x reference)
//
#include <hip/hip_runtime.h>
#include <cstdint>

#define NE_N   100000
#define NPER_N 50000
#define HD     128
#define OUTD   64
#define NEE    1600000
#define NPE    800000
#define NEP    800000

static inline int ceil_div(long long a, long long b){ return (int)((a + b - 1)/b); }

__device__ __forceinline__ float4 ld4(const float* p){ return *reinterpret_cast<const float4*>(p); }
__device__ __forceinline__ void st4(float* p, float4 v){ *reinterpret_cast<float4*>(p) = v; }
__device__ __forceinline__ float4 f4fma(float s, float4 a, float4 b){
    b.x += s*a.x; b.y += s*a.y; b.z += s*a.z; b.w += s*a.w; return b; }
__device__ __forceinline__ float4 f4add(float4 a, float4 b){
    a.x+=b.x; a.y+=b.y; a.z+=b.z; a.w+=b.w; return a; }
__device__ __forceinline__ float4 f4relu(float4 a){
    a.x=fmaxf(a.x,0.f); a.y=fmaxf(a.y,0.f); a.z=fmaxf(a.z,0.f); a.w=fmaxf(a.w,0.f); return a; }

// ---------------- GEMM: C[N x M] = (relu?)(A[N x K] @ W[K x M] (+ bias)) ----------------
// block dim3(M/8, BY); each thread: 4 rows x 8 cols. W staged in LDS; A rows read via
// broadcast global loads (16 lanes share each 16B request -> L1 broadcast).
template<int K, int M, int BY, bool RELU, bool BIAS>
__global__ __launch_bounds__(256)
void gemm_kernel(const float* __restrict__ A, const float* __restrict__ W,
                 const float* __restrict__ bias, float* __restrict__ C, int N)
{
    __shared__ float Ws[K*M];
    const int tid  = threadIdx.y*blockDim.x + threadIdx.x;
    const int nthr = (M/8)*BY;
    for (int i = tid; i < K*M/4; i += nthr)
        reinterpret_cast<float4*>(Ws)[i] = reinterpret_cast<const float4*>(W)[i];
    __syncthreads();

    const int tx = threadIdx.x, ty = threadIdx.y;
    const int c0 = tx*8;
    const int r0 = blockIdx.x*(4*BY) + ty*4;

    const float* Ar[4];
#pragma unroll
    for (int i=0;i<4;i++){ int r=r0+i; if (r>N-1) r=N-1; Ar[i]=A+(size_t)r*K; }

    float4 acc0[4], acc1[4];
#pragma unroll
    for (int i=0;i<4;i++){ acc0[i]=make_float4(0,0,0,0); acc1[i]=make_float4(0,0,0,0); }

    for (int k=0;k<K;k+=4){
        float4 a[4];
#pragma unroll
        for (int i=0;i<4;i++) a[i]=ld4(Ar[i]+k);
#pragma unroll
        for (int kk=0;kk<4;kk++){
            float4 w0 = ld4(&Ws[(k+kk)*M + c0]);
            float4 w1 = ld4(&Ws[(k+kk)*M + c0 + 4]);
#pragma unroll
            for (int i=0;i<4;i++){
                float av = (kk==0)?a[i].x:(kk==1)?a[i].y:(kk==2)?a[i].z:a[i].w;
                acc0[i]=f4fma(av,w0,acc0[i]);
                acc1[i]=f4fma(av,w1,acc1[i]);
            }
        }
    }

    float4 b0=make_float4(0,0,0,0), b1=b0;
    if (BIAS){ b0=ld4(bias+c0); b1=ld4(bias+c0+4); }
#pragma unroll
    for (int i=0;i<4;i++){
        int r=r0+i;
        if (r<N){
            float4 o0=acc0[i], o1=acc1[i];
            if (BIAS){ o0=f4add(o0,b0); o1=f4add(o1,b1); }
            if (RELU){ o0=f4relu(o0); o1=f4relu(o1); }
            st4(&C[(size_t)r*M+c0],   o0);
            st4(&C[(size_t)r*M+c0+4], o1);
        }
    }
}

// ---------------- edge kernels ----------------
__global__ void count_kernel(const int* __restrict__ dst, float* __restrict__ cnt, int E){
    int i = blockIdx.x*blockDim.x + threadIdx.x;
    if (i < E) atomicAdd(&cnt[dst[i]], 1.0f);
}
__global__ void inv_kernel(float* __restrict__ c, int n){
    int i = blockIdx.x*blockDim.x + threadIdx.x;
    if (i < n) c[i] = 1.0f/fmaxf(c[i], 1.0f);
}
__global__ void relu_kernel(float* __restrict__ x, int n){
    int i = blockIdx.x*blockDim.x + threadIdx.x;
    if (i < n) x[i] = fmaxf(x[i], 0.0f);
}

// one wave per edge, F=128: float2 per lane
__global__ void scatter128(const float* __restrict__ proj, const int* __restrict__ src,
                           const int* __restrict__ dst, const float* __restrict__ inv,
                           float* __restrict__ out, int E){
    int wid  = (blockIdx.x*blockDim.x + threadIdx.x) >> 6;
    int lane = threadIdx.x & 63;
    if (wid >= E) return;
    int s = src[wid], d = dst[wid];
    float sc = inv[d];
    float2 v = *reinterpret_cast<const float2*>(&proj[(size_t)s*128 + lane*2]);
    atomicAdd(&out[(size_t)d*128 + lane*2    ], v.x*sc);
    atomicAdd(&out[(size_t)d*128 + lane*2 + 1], v.y*sc);
}
// one wave per edge, F=64: one float per lane
__global__ void scatter64(const float* __restrict__ proj, const int* __restrict__ src,
                          const int* __restrict__ dst, const float* __restrict__ inv,
                          float* __restrict__ out, int E){
    int wid  = (blockIdx.x*blockDim.x + threadIdx.x) >> 6;
    int lane = threadIdx.x & 63;
    if (wid >= E) return;
    int s = src[wid], d = dst[wid];
    float sc = inv[d];
    atomicAdd(&out[(size_t)d*64 + lane], proj[(size_t)s*64 + lane]*sc);
}

// ---------------- GAT ----------------
__device__ __forceinline__ unsigned fenc(float f){
    unsigned b = __float_as_uint(f);
    return (b & 0x80000000u) ? ~b : (b | 0x80000000u);
}
__device__ __forceinline__ float fdec(unsigned u){
    return __uint_as_float((u & 0x80000000u) ? (u & 0x7fffffffu) : ~u);
}
__global__ void gat_max_kernel(const int* __restrict__ src, const int* __restrict__ dst,
                               const float* __restrict__ as, const float* __restrict__ ad,
                               unsigned* __restrict__ m, int E){
    int i = blockIdx.x*blockDim.x + threadIdx.x;
    if (i >= E) return;
    float e = as[src[i]] + ad[dst[i]];
    e = e > 0.f ? e : 0.2f*e;
    atomicMax(&m[dst[i]], fenc(e));
}
__global__ void mdec_kernel(unsigned* __restrict__ m, int n){
    int i = blockIdx.x*blockDim.x + threadIdx.x;
    if (i >= n) return;
    float f = fdec(m[i]);
    reinterpret_cast<float*>(m)[i] = f;
}
__global__ void gat_den_kernel(const int* __restrict__ src, const int* __restrict__ dst,
                               const float* __restrict__ as, const float* __restrict__ ad,
                               const float* __restrict__ m, float* __restrict__ den, int E){
    int i = blockIdx.x*blockDim.x + threadIdx.x;
    if (i >= E) return;
    int s = src[i], d = dst[i];
    float e = as[s] + ad[d];
    e = e > 0.f ? e : 0.2f*e;
    atomicAdd(&den[d], expf(e - m[d]));
}
// one wave per edge, OUT=64 floats
__global__ void gat_out_kernel(const int* __restrict__ src, const int* __restrict__ dst,
                               const float* __restrict__ as, const float* __restrict__ ad,
                               const float* __restrict__ m, const float* __restrict__ den,
                               const float* __restrict__ zs, float* __restrict__ out, int E){
    int wid  = (blockIdx.x*blockDim.x + threadIdx.x) >> 6;
    int lane = threadIdx.x & 63;
    if (wid >= E) return;
    int s = src[wid], d = dst[wid];
    float e = as[s] + ad[d];
    e = e > 0.f ? e : 0.2f*e;
    float alpha = expf(e - m[d]) / den[d];
    atomicAdd(&out[(size_t)d*64 + lane], zs[(size_t)s*64 + lane]*alpha);
}

// GEMV: out[i] = dot(X[i,:64], w)
__global__ void rowdot64(const float* __restrict__ X, const float* __restrict__ w,
                         float* __restrict__ out, int N){
    int wid  = (blockIdx.x*blockDim.x + threadIdx.x) >> 6;
    int lane = threadIdx.x & 63;
    if (wid >= N) return;
    float v = X[(size_t)wid*64 + lane]*w[lane];
    for (int o=32;o;o>>=1) v += __shfl_xor(v,o,64);
    if (lane==0) out[wid]=v;
}
// out[i] = dot(X[i,:128], w)
__global__ void rowdot128(const float* __restrict__ X, const float* __restrict__ w,
                          float* __restrict__ out, int N){
    int wid  = (blockIdx.x*blockDim.x + threadIdx.x) >> 6;
    int lane = threadIdx.x & 63;
    if (wid >= N) return;
    float v = X[(size_t)wid*128 + lane]*w[lane] + X[(size_t)wid*128 + 64 + lane]*w[64+lane];
    for (int o=32;o;o>>=1) v += __shfl_xor(v,o,64);
    if (lane==0) out[wid]=v;
}

// small precompute: Wsum = Wr_ee+Wr_pe; bsum1 = bl_ee+bl_pe; b2sum = s2_pe_bl+gat_b; v = Wdst@adst
__global__ void prep_kernel(const float* __restrict__ Wr_ee, const float* __restrict__ Wr_pe,
                            const float* __restrict__ bl_ee, const float* __restrict__ bl_pe,
                            const float* __restrict__ s2_pe_bl, const float* __restrict__ gat_b,
                            const float* __restrict__ Wdst, const float* __restrict__ adst,
                            float* __restrict__ Wsum, float* __restrict__ bsum1,
                            float* __restrict__ b2sum, float* __restrict__ v){
    int t = threadIdx.x;
    for (int i=t;i<HD*HD;i+=256) Wsum[i]=Wr_ee[i]+Wr_pe[i];
    if (t<HD) bsum1[t]=bl_ee[t]+bl_pe[t];
    if (t<OUTD) b2sum[t]=s2_pe_bl[t]+gat_b[t];
    if (t<HD){
        float s=0.f;
        for (int c=0;c<OUTD;c++) s += Wdst[t*OUTD+c]*adst[c];
        v[t]=s;
    }
}

// ---------------- workspace layout (floats) ----------------
constexpr size_t OFF_HEMP  = 0;          // 12.8M   (reused later: zs / p2pe / p2ep)
constexpr size_t OFF_HPER  = 12800000;   // 6.4M
constexpr size_t OFF_EMP1  = 19200000;   // 12.8M
constexpr size_t OFF_PER1  = 32000000;   // 6.4M
constexpr size_t OFF_PROJ  = 38400000;   // 12.8M
constexpr size_t OFF_ZS    = 0;          // NE*64  = 6.4M
constexpr size_t OFF_P2PE  = 6400000;    // NPER*64= 3.2M
constexpr size_t OFF_P2EP  = 9600000;    // NE*64  = 6.4M  (ends 16.0M < 19.2M ok)
constexpr size_t OFF_CNT_EE= 51200000;   // 100k
constexpr size_t OFF_CNT_PE= 51300000;   // 100k
constexpr size_t OFF_CNT_EP= 51400000;   // 50k
constexpr size_t OFF_AS    = 51450000;   // 100k
constexpr size_t OFF_AD    = 51550000;   // 100k
constexpr size_t OFF_M     = 51650000;   // 100k
constexpr size_t OFF_DEN   = 51750000;   // 100k
constexpr size_t OFF_WSUM  = 51850000;   // 16384
constexpr size_t OFF_BSUM1 = 51866384;   // 128
constexpr size_t OFF_B2SUM = 51866512;   // 64
constexpr size_t OFF_V     = 51866576;   // 128
// total 51,866,704 floats = ~198 MiB of d_ws

extern "C" void kernel_launch(void* const* d_in, const int* in_sizes, int n_in,
                              void* d_out, int out_size, void* d_ws, size_t ws_size,
                              hipStream_t stream)
{
    const float* x_emp = (const float*)d_in[0];
    const float* x_per = (const float*)d_in[1];
    const int* ee_src = (const int*)d_in[2];
    const int* ee_dst = (const int*)d_in[3];
    const int* pe_src = (const int*)d_in[4];
    const int* pe_dst = (const int*)d_in[5];
    const int* ep_src = (const int*)d_in[6];
    const int* ep_dst = (const int*)d_in[7];
    const float* lin_emp_w=(const float*)d_in[8],  *lin_emp_b=(const float*)d_in[9];
    const float* lin_per_w=(const float*)d_in[10], *lin_per_b=(const float*)d_in[11];
    const float* s1_ee_Wl=(const float*)d_in[12], *s1_ee_bl=(const float*)d_in[13], *s1_ee_Wr=(const float*)d_in[14];
    const float* s1_pe_Wl=(const float*)d_in[15], *s1_pe_bl=(const float*)d_in[16], *s1_pe_Wr=(const float*)d_in[17];
    const float* s1_ep_Wl=(const float*)d_in[18], *s1_ep_bl=(const float*)d_in[19], *s1_ep_Wr=(const float*)d_in[20];
    const float* gat_Wsrc=(const float*)d_in[21], *gat_Wdst=(const float*)d_in[22];
    const float* gat_asrc=(const float*)d_in[23], *gat_adst=(const float*)d_in[24], *gat_b=(const float*)d_in[25];
    const float* s2_pe_Wl=(const float*)d_in[26], *s2_pe_bl=(const float*)d_in[27], *s2_pe_Wr=(const float*)d_in[28];
    const float* s2_ep_Wl=(const float*)d_in[29], *s2_ep_bl=(const float*)d_in[30], *s2_ep_Wr=(const float*)d_in[31];

    float* ws = (float*)d_ws;
    float* out_emp = (float*)d_out;
    float* out_per = out_emp + (size_t)NE_N*OUTD;

    float* h_emp = ws + OFF_HEMP;
    float* h_per = ws + OFF_HPER;
    float* emp1  = ws + OFF_EMP1;
    float* per1  = ws + OFF_PER1;
    float* proj  = ws + OFF_PROJ;
    float* zs    = ws + OFF_ZS;
    float* p2pe  = ws + OFF_P2PE;
    float* p2ep  = ws + OFF_P2EP;
    float* inv_ee= ws + OFF_CNT_EE;
    float* inv_pe= ws + OFF_CNT_PE;
    float* inv_ep= ws + OFF_CNT_EP;
    float* a_s   = ws + OFF_AS;
    float* a_d   = ws + OFF_AD;
    float* m_buf = ws + OFF_M;
    float* den   = ws + OFF_DEN;
    float* Wsum  = ws + OFF_WSUM;
    float* bsum1 = ws + OFF_BSUM1;
    float* b2sum = ws + OFF_B2SUM;
    float* vvec  = ws + OFF_V;

    dim3 blk128(16,16);  // M=128 GEMMs: BM=64
    dim3 blk64 (8,32);   // M=64  GEMMs: BM=128

    // zero counters / gat state
    hipMemsetAsync(ws + OFF_CNT_EE, 0, 250000*sizeof(float), stream);
    hipMemsetAsync(ws + OFF_M,      0, 200000*sizeof(float), stream);

    prep_kernel<<<1,256,0,stream>>>(s1_ee_Wr, s1_pe_Wr, s1_ee_bl, s1_pe_bl,
                                    s2_pe_bl, gat_b, gat_Wdst, gat_adst,
                                    Wsum, bsum1, b2sum, vvec);

    count_kernel<<<ceil_div(NEE,256),256,0,stream>>>(ee_dst, inv_ee, NEE);
    count_kernel<<<ceil_div(NPE,256),256,0,stream>>>(pe_dst, inv_pe, NPE);
    count_kernel<<<ceil_div(NEP,256),256,0,stream>>>(ep_dst, inv_ep, NEP);
    inv_kernel<<<ceil_div(250000,256),256,0,stream>>>(inv_ee, 250000);

    // input projections
    gemm_kernel<64,128,16,true,true><<<ceil_div(NE_N,64),blk128,0,stream>>>(x_emp, lin_emp_w, lin_emp_b, h_emp, NE_N);
    gemm_kernel<32,128,16,true,true><<<ceil_div(NPER_N,64),blk128,0,stream>>>(x_per, lin_per_w, lin_per_b, h_per, NPER_N);

    // conv1: emp1 = relu( h_emp@(Wr_ee+Wr_pe) + bl_ee+bl_pe + mean_ee(h_emp@Wl_ee) + mean_pe(h_per@Wl_pe) )
    gemm_kernel<128,128,16,false,true><<<ceil_div(NE_N,64),blk128,0,stream>>>(h_emp, Wsum, bsum1, emp1, NE_N);
    gemm_kernel<128,128,16,false,false><<<ceil_div(NE_N,64),blk128,0,stream>>>(h_emp, s1_ee_Wl, nullptr, proj, NE_N);
    scatter128<<<ceil_div((long long)NEE*64,256),256,0,stream>>>(proj, ee_src, ee_dst, inv_ee, emp1, NEE);
    gemm_kernel<128,128,16,false,false><<<ceil_div(NPER_N,64),blk128,0,stream>>>(h_per, s1_pe_Wl, nullptr, proj, NPER_N);
    scatter128<<<ceil_div((long long)NPE*64,256),256,0,stream>>>(proj, pe_src, pe_dst, inv_pe, emp1, NPE);
    relu_kernel<<<ceil_div((long long)NE_N*HD,256),256,0,stream>>>(emp1, NE_N*HD);

    // conv1: per1 = relu( h_per@Wr_ep + bl_ep + mean_ep(h_emp@Wl_ep) )
    gemm_kernel<128,128,16,false,true><<<ceil_div(NPER_N,64),blk128,0,stream>>>(h_per, s1_ep_Wr, s1_ep_bl, per1, NPER_N);
    gemm_kernel<128,128,16,false,false><<<ceil_div(NE_N,64),blk128,0,stream>>>(h_emp, s1_ep_Wl, nullptr, proj, NE_N);
    scatter128<<<ceil_div((long long)NEP*64,256),256,0,stream>>>(proj, ep_src, ep_dst, inv_ep, per1, NEP);
    relu_kernel<<<ceil_div((long long)NPER_N*HD,256),256,0,stream>>>(per1, NPER_N*HD);

    // conv2 GAT prep: zs = emp1@Wsrc ; a_s = zs@asrc ; a_d = emp1@(Wdst@adst)
    gemm_kernel<128,64,32,false,false><<<ceil_div(NE_N,128),blk64,0,stream>>>(emp1, gat_Wsrc, nullptr, zs, NE_N);
    rowdot64 <<<ceil_div(NE_N,4),256,0,stream>>>(zs,   gat_asrc, a_s, NE_N);
    rowdot128<<<ceil_div(NE_N,4),256,0,stream>>>(emp1, vvec,     a_d, NE_N);

    // GAT softmax passes
    gat_max_kernel<<<ceil_div(NEE,256),256,0,stream>>>(ee_src, ee_dst, a_s, a_d, (unsigned*)m_buf, NEE);
    mdec_kernel<<<ceil_div(NE_N,256),256,0,stream>>>((unsigned*)m_buf, NE_N);
    gat_den_kernel<<<ceil_div(NEE,256),256,0,stream>>>(ee_src, ee_dst, a_s, a_d, m_buf, den, NEE);

    // emp2 = emp1@s2_pe_Wr + (s2_pe_bl+gat_b) + mean_pe(per1@s2_pe_Wl) + gat_out
    gemm_kernel<128,64,32,false,true><<<ceil_div(NE_N,128),blk64,0,stream>>>(emp1, s2_pe_Wr, b2sum, out_emp, NE_N);
    gemm_kernel<128,64,32,false,false><<<ceil_div(NPER_N,128),blk64,0,stream>>>(per1, s2_pe_Wl, nullptr, p2pe, NPER_N);
    scatter64<<<ceil_div((long long)NPE*64,256),256,0,stream>>>(p2pe, pe_src, pe_dst, inv_pe, out_emp, NPE);
    gat_out_kernel<<<ceil_div((long long)NEE*64,256),256,0,stream>>>(ee_src, ee_dst, a_s, a_d, m_buf, den, zs, out_emp, NEE);

    // per2 = per1@s2_ep_Wr + bl + mean_ep(emp1@s2_ep_Wl)
    gemm_kernel<128,64,32,false,true><<<ceil_div(NPER_N,128),blk64,0,stream>>>(per1, s2_ep_Wr, s2_ep_bl, out_per, NPER_N);
    gemm_kernel<128,64,32,false,false><<<ceil_div(NE_N,128),blk64,0,stream>>>(emp1, s2_ep_Wl, nullptr, p2ep, NE_N);
    scatter64<<<ceil_div((long long)NEP*64,256),256,0,stream>>>(p2ep, ep_src, ep_dst, inv_ep, out_per, NEP);
}

// Round 2
// 1556.420 us; speedup vs baseline: 2.7079x; 2.7079x over previous
//
#include <hip/hip_runtime.h>
#include <cstdint>

#define NE_N   100000
#define NPER_N 50000
#define HD     128
#define OUTD   64
#define NEE    1600000
#define NPE    800000
#define NEP    800000

static inline int ceil_div(long long a, long long b){ return (int)((a + b - 1)/b); }

__device__ __forceinline__ float4 ld4(const float* p){ return *reinterpret_cast<const float4*>(p); }
__device__ __forceinline__ void st4(float* p, float4 v){ *reinterpret_cast<float4*>(p) = v; }
__device__ __forceinline__ float4 f4fma(float s, float4 a, float4 b){
    b.x += s*a.x; b.y += s*a.y; b.z += s*a.z; b.w += s*a.w; return b; }
__device__ __forceinline__ float4 f4add(float4 a, float4 b){
    a.x+=b.x; a.y+=b.y; a.z+=b.z; a.w+=b.w; return a; }
__device__ __forceinline__ float4 f4relu(float4 a){
    a.x=fmaxf(a.x,0.f); a.y=fmaxf(a.y,0.f); a.z=fmaxf(a.z,0.f); a.w=fmaxf(a.w,0.f); return a; }

// ---------------- GEMM: C[N x M] = (relu?)(A[N x K] @ W[K x M] (+ bias)) ----------------
template<int K, int M, int BY, bool RELU, bool BIAS>
__global__ __launch_bounds__(256)
void gemm_kernel(const float* __restrict__ A, const float* __restrict__ W,
                 const float* __restrict__ bias, float* __restrict__ C, int N)
{
    __shared__ float Ws[K*M];
    const int tid  = threadIdx.y*blockDim.x + threadIdx.x;
    const int nthr = (M/8)*BY;
    for (int i = tid; i < K*M/4; i += nthr)
        reinterpret_cast<float4*>(Ws)[i] = reinterpret_cast<const float4*>(W)[i];
    __syncthreads();

    const int tx = threadIdx.x, ty = threadIdx.y;
    const int c0 = tx*8;
    const int r0 = blockIdx.x*(4*BY) + ty*4;

    const float* Ar[4];
#pragma unroll
    for (int i=0;i<4;i++){ int r=r0+i; if (r>N-1) r=N-1; Ar[i]=A+(size_t)r*K; }

    float4 acc0[4], acc1[4];
#pragma unroll
    for (int i=0;i<4;i++){ acc0[i]=make_float4(0,0,0,0); acc1[i]=make_float4(0,0,0,0); }

    for (int k=0;k<K;k+=4){
        float4 a[4];
#pragma unroll
        for (int i=0;i<4;i++) a[i]=ld4(Ar[i]+k);
#pragma unroll
        for (int kk=0;kk<4;kk++){
            float4 w0 = ld4(&Ws[(k+kk)*M + c0]);
            float4 w1 = ld4(&Ws[(k+kk)*M + c0 + 4]);
#pragma unroll
            for (int i=0;i<4;i++){
                float av = (kk==0)?a[i].x:(kk==1)?a[i].y:(kk==2)?a[i].z:a[i].w;
                acc0[i]=f4fma(av,w0,acc0[i]);
                acc1[i]=f4fma(av,w1,acc1[i]);
            }
        }
    }

    float4 b0=make_float4(0,0,0,0), b1=b0;
    if (BIAS){ b0=ld4(bias+c0); b1=ld4(bias+c0+4); }
#pragma unroll
    for (int i=0;i<4;i++){
        int r=r0+i;
        if (r<N){
            float4 o0=acc0[i], o1=acc1[i];
            if (BIAS){ o0=f4add(o0,b0); o1=f4add(o1,b1); }
            if (RELU){ o0=f4relu(o0); o1=f4relu(o1); }
            st4(&C[(size_t)r*M+c0],   o0);
            st4(&C[(size_t)r*M+c0+4], o1);
        }
    }
}

// ---------------- CSR build ----------------
__global__ void count_int(const int* __restrict__ dst, int* __restrict__ cnt, int E){
    int i = blockIdx.x*blockDim.x + threadIdx.x;
    if (i < E) atomicAdd(&cnt[dst[i]], 1);
}
// block of 256 scans 1024 elements -> local exclusive offsets + per-block total
__global__ __launch_bounds__(256)
void scan_block(const int* __restrict__ cnt, int* __restrict__ off,
                int* __restrict__ partial, int n){
    __shared__ int sh[256];
    int t = threadIdx.x;
    int base = blockIdx.x*1024 + t*4;
    int v0 = (base  <n)?cnt[base  ]:0;
    int v1 = (base+1<n)?cnt[base+1]:0;
    int v2 = (base+2<n)?cnt[base+2]:0;
    int v3 = (base+3<n)?cnt[base+3]:0;
    int tsum = v0+v1+v2+v3;
    sh[t]=tsum; __syncthreads();
    for (int d=1; d<256; d<<=1){
        int x = (t>=d)? sh[t-d] : 0;
        __syncthreads();
        sh[t] += x;
        __syncthreads();
    }
    int ex = sh[t]-tsum;
    if (base  <n) off[base  ]=ex;
    if (base+1<n) off[base+1]=ex+v0;
    if (base+2<n) off[base+2]=ex+v0+v1;
    if (base+3<n) off[base+3]=ex+v0+v1+v2;
    if (t==255) partial[blockIdx.x]=sh[255];
}
__global__ void scan_partial(int* __restrict__ partial, int nb){
    if (threadIdx.x==0 && blockIdx.x==0){
        int run=0;
        for (int i=0;i<nb;i++){ int v=partial[i]; partial[i]=run; run+=v; }
    }
}
__global__ void add_base(int* __restrict__ off, const int* __restrict__ partial, int n, int total){
    int i = blockIdx.x*blockDim.x + threadIdx.x;
    if (i < n) off[i] += partial[i>>10];
    else if (i == n) off[n] = total;
}
// consumes cnt (decrements to 0)
__global__ void fill_csr(const int* __restrict__ src, const int* __restrict__ dst,
                         const int* __restrict__ off, int* __restrict__ cnt,
                         int* __restrict__ csr, int E){
    int i = blockIdx.x*blockDim.x + threadIdx.x;
    if (i >= E) return;
    int d = dst[i];
    int old = atomicAdd(&cnt[d], -1);
    csr[off[d] + old - 1] = src[i];
}

// ---------------- gather-side aggregation (no atomics) ----------------
// emp1[d] = relu(emp1[d] + mean_ee(proj_ee) + mean_pe(proj_pe)), F=128
__global__ __launch_bounds__(256)
void agg_emp1(const float* __restrict__ proj_ee, const float* __restrict__ proj_pe,
              const int* __restrict__ ee_off, const int* __restrict__ ee_csr,
              const int* __restrict__ pe_off, const int* __restrict__ pe_csr,
              float* __restrict__ emp1){
    int w    = (blockIdx.x*blockDim.x + threadIdx.x) >> 6;
    int lane = threadIdx.x & 63;
    if (w >= NE_N) return;
    float ax=0.f, ay=0.f;
    int b = ee_off[w], e = ee_off[w+1];
    for (int j=b;j<e;j++){
        int s = ee_csr[j];
        float2 v = *reinterpret_cast<const float2*>(&proj_ee[(size_t)s*128 + lane*2]);
        ax += v.x; ay += v.y;
    }
    float s1 = 1.f/fmaxf((float)(e-b),1.f);
    float bx=0.f, by=0.f;
    b = pe_off[w]; e = pe_off[w+1];
    for (int j=b;j<e;j++){
        int s = pe_csr[j];
        float2 v = *reinterpret_cast<const float2*>(&proj_pe[(size_t)s*128 + lane*2]);
        bx += v.x; by += v.y;
    }
    float s2 = 1.f/fmaxf((float)(e-b),1.f);
    float* row = &emp1[(size_t)w*128 + lane*2];
    float2 self = *reinterpret_cast<float2*>(row);
    float2 o;
    o.x = fmaxf(self.x + ax*s1 + bx*s2, 0.f);
    o.y = fmaxf(self.y + ay*s1 + by*s2, 0.f);
    *reinterpret_cast<float2*>(row) = o;
}
// per1[d] = relu(per1[d] + mean_ep(proj_ep)), F=128
__global__ __launch_bounds__(256)
void agg_per1(const float* __restrict__ proj_ep,
              const int* __restrict__ ep_off, const int* __restrict__ ep_csr,
              float* __restrict__ per1){
    int w    = (blockIdx.x*blockDim.x + threadIdx.x) >> 6;
    int lane = threadIdx.x & 63;
    if (w >= NPER_N) return;
    float ax=0.f, ay=0.f;
    int b = ep_off[w], e = ep_off[w+1];
    for (int j=b;j<e;j++){
        int s = ep_csr[j];
        float2 v = *reinterpret_cast<const float2*>(&proj_ep[(size_t)s*128 + lane*2]);
        ax += v.x; ay += v.y;
    }
    float s1 = 1.f/fmaxf((float)(e-b),1.f);
    float* row = &per1[(size_t)w*128 + lane*2];
    float2 self = *reinterpret_cast<float2*>(row);
    float2 o;
    o.x = fmaxf(self.x + ax*s1, 0.f);
    o.y = fmaxf(self.y + ay*s1, 0.f);
    *reinterpret_cast<float2*>(row) = o;
}
// out_per[d] += mean_ep(p2ep), F=64
__global__ __launch_bounds__(256)
void agg_per2(const float* __restrict__ p2ep,
              const int* __restrict__ ep_off, const int* __restrict__ ep_csr,
              float* __restrict__ out){
    int w    = (blockIdx.x*blockDim.x + threadIdx.x) >> 6;
    int lane = threadIdx.x & 63;
    if (w >= NPER_N) return;
    float a=0.f;
    int b = ep_off[w], e = ep_off[w+1];
    for (int j=b;j<e;j++) a += p2ep[(size_t)ep_csr[j]*64 + lane];
    float s1 = 1.f/fmaxf((float)(e-b),1.f);
    out[(size_t)w*64 + lane] += a*s1;
}
// out_emp[d] += GAT_ee(d) + mean_pe(p2pe), F=64, fully fused, no atomics
__global__ __launch_bounds__(256)
void gat_sage_emp2(const int* __restrict__ ee_off, const int* __restrict__ ee_csr,
                   const int* __restrict__ pe_off, const int* __restrict__ pe_csr,
                   const float* __restrict__ as, const float* __restrict__ ad,
                   const float* __restrict__ zs, const float* __restrict__ p2pe,
                   float* __restrict__ out){
    int w    = (blockIdx.x*blockDim.x + threadIdx.x) >> 6;
    int lane = threadIdx.x & 63;
    if (w >= NE_N) return;

    float acc = 0.f;
    int b = ee_off[w], e = ee_off[w+1];
    if (e > b){
        float add = ad[w];
        // phase A: lanes parallel over neighbors -> max, then denom
        float m = -INFINITY;
        for (int j=b+lane; j<e; j+=64){
            float ev = as[ee_csr[j]] + add;
            ev = ev > 0.f ? ev : 0.2f*ev;
            m = fmaxf(m, ev);
        }
        for (int o=32;o;o>>=1) m = fmaxf(m, __shfl_xor(m, o, 64));
        float den = 0.f;
        for (int j=b+lane; j<e; j+=64){
            float ev = as[ee_csr[j]] + add;
            ev = ev > 0.f ? ev : 0.2f*ev;
            den += expf(ev - m);
        }
        for (int o=32;o;o>>=1) den += __shfl_xor(den, o, 64);
        float invden = 1.f/den;
        // phase B: serial over neighbors, lane = feature
        for (int j=b;j<e;j++){
            int s = ee_csr[j];
            float ev = as[s] + add;
            ev = ev > 0.f ? ev : 0.2f*ev;
            float alpha = expf(ev - m)*invden;
            acc += zs[(size_t)s*64 + lane]*alpha;
        }
    }
    // SAGE pe relation
    float a2 = 0.f;
    b = pe_off[w]; e = pe_off[w+1];
    for (int j=b;j<e;j++) a2 += p2pe[(size_t)pe_csr[j]*64 + lane];
    float s2 = 1.f/fmaxf((float)(e-b),1.f);
    out[(size_t)w*64 + lane] += acc + a2*s2;
}

// GEMV helpers
__global__ void rowdot64(const float* __restrict__ X, const float* __restrict__ w,
                         float* __restrict__ out, int N){
    int wid  = (blockIdx.x*blockDim.x + threadIdx.x) >> 6;
    int lane = threadIdx.x & 63;
    if (wid >= N) return;
    float v = X[(size_t)wid*64 + lane]*w[lane];
    for (int o=32;o;o>>=1) v += __shfl_xor(v,o,64);
    if (lane==0) out[wid]=v;
}
__global__ void rowdot128(const float* __restrict__ X, const float* __restrict__ w,
                          float* __restrict__ out, int N){
    int wid  = (blockIdx.x*blockDim.x + threadIdx.x) >> 6;
    int lane = threadIdx.x & 63;
    if (wid >= N) return;
    float v = X[(size_t)wid*128 + lane]*w[lane] + X[(size_t)wid*128 + 64 + lane]*w[64+lane];
    for (int o=32;o;o>>=1) v += __shfl_xor(v,o,64);
    if (lane==0) out[wid]=v;
}

__global__ void prep_kernel(const float* __restrict__ Wr_ee, const float* __restrict__ Wr_pe,
                            const float* __restrict__ bl_ee, const float* __restrict__ bl_pe,
                            const float* __restrict__ s2_pe_bl, const float* __restrict__ gat_b,
                            const float* __restrict__ Wdst, const float* __restrict__ adst,
                            float* __restrict__ Wsum, float* __restrict__ bsum1,
                            float* __restrict__ b2sum, float* __restrict__ v){
    int t = threadIdx.x;
    for (int i=t;i<HD*HD;i+=256) Wsum[i]=Wr_ee[i]+Wr_pe[i];
    if (t<HD) bsum1[t]=bl_ee[t]+bl_pe[t];
    if (t<OUTD) b2sum[t]=s2_pe_bl[t]+gat_b[t];
    if (t<HD){
        float s=0.f;
        for (int c=0;c<OUTD;c++) s += Wdst[t*OUTD+c]*adst[c];
        v[t]=s;
    }
}

// ---------------- workspace layout (4-byte units) ----------------
constexpr size_t OFF_A     = 0;          // h_emp 12.8M ; later: as @ +0, ad @ +100000
constexpr size_t OFF_B     = 12800000;   // h_per 6.4M
constexpr size_t OFF_C     = 19200000;   // emp1 12.8M
constexpr size_t OFF_D     = 32000000;   // per1 6.4M
constexpr size_t OFF_E     = 38400000;   // proj_ee 12.8M ; later proj_ep ; later p2pe(3.2M)+p2ep(6.4M)
constexpr size_t OFF_F     = 51200000;   // proj_pe 6.4M ; later zs 6.4M
constexpr size_t OFF_WSUM  = 57600000;   // 16384
constexpr size_t OFF_BSUM1 = 57616384;   // 128
constexpr size_t OFF_B2SUM = 57616512;   // 64
constexpr size_t OFF_V     = 57616576;   // 128
// int region
constexpr size_t OFF_EE_CNT = 57700000;  // 100000
constexpr size_t OFF_EE_OFF = 57800000;  // 100001
constexpr size_t OFF_PE_CNT = 57900008;  // 100000
constexpr size_t OFF_PE_OFF = 58000008;  // 100001
constexpr size_t OFF_EP_CNT = 58100016;  // 50000
constexpr size_t OFF_EP_OFF = 58150016;  // 50001
constexpr size_t OFF_PART   = 58200024;  // 256
constexpr size_t OFF_EE_CSR = 58200280;  // 1.6M
constexpr size_t OFF_PE_CSR = 59800280;  // 0.8M
constexpr size_t OFF_EP_CSR = 60600280;  // 0.8M
// end ~61.4M units = 246 MB

extern "C" void kernel_launch(void* const* d_in, const int* in_sizes, int n_in,
                              void* d_out, int out_size, void* d_ws, size_t ws_size,
                              hipStream_t stream)
{
    const float* x_emp = (const float*)d_in[0];
    const float* x_per = (const float*)d_in[1];
    const int* ee_src = (const int*)d_in[2];
    const int* ee_dst = (const int*)d_in[3];
    const int* pe_src = (const int*)d_in[4];
    const int* pe_dst = (const int*)d_in[5];
    const int* ep_src = (const int*)d_in[6];
    const int* ep_dst = (const int*)d_in[7];
    const float* lin_emp_w=(const float*)d_in[8],  *lin_emp_b=(const float*)d_in[9];
    const float* lin_per_w=(const float*)d_in[10], *lin_per_b=(const float*)d_in[11];
    const float* s1_ee_Wl=(const float*)d_in[12], *s1_ee_bl=(const float*)d_in[13], *s1_ee_Wr=(const float*)d_in[14];
    const float* s1_pe_Wl=(const float*)d_in[15], *s1_pe_bl=(const float*)d_in[16], *s1_pe_Wr=(const float*)d_in[17];
    const float* s1_ep_Wl=(const float*)d_in[18], *s1_ep_bl=(const float*)d_in[19], *s1_ep_Wr=(const float*)d_in[20];
    const float* gat_Wsrc=(const float*)d_in[21], *gat_Wdst=(const float*)d_in[22];
    const float* gat_asrc=(const float*)d_in[23], *gat_adst=(const float*)d_in[24], *gat_b=(const float*)d_in[25];
    const float* s2_pe_Wl=(const float*)d_in[26], *s2_pe_bl=(const float*)d_in[27], *s2_pe_Wr=(const float*)d_in[28];
    const float* s2_ep_Wl=(const float*)d_in[29], *s2_ep_bl=(const float*)d_in[30], *s2_ep_Wr=(const float*)d_in[31];

    float* ws = (float*)d_ws;
    int*   wi = (int*)d_ws;
    float* out_emp = (float*)d_out;
    float* out_per = out_emp + (size_t)NE_N*OUTD;

    float* h_emp = ws + OFF_A;
    float* h_per = ws + OFF_B;
    float* emp1  = ws + OFF_C;
    float* per1  = ws + OFF_D;
    float* proj_ee = ws + OFF_E;      // also proj_ep later
    float* proj_pe = ws + OFF_F;      // also zs later
    float* p2pe  = ws + OFF_E;                 // NPER*64 = 3.2M
    float* p2ep  = ws + OFF_E + 3200000;       // NE*64  = 6.4M
    float* zs    = ws + OFF_F;
    float* a_s   = ws + OFF_A;                 // h_emp dead by then
    float* a_d   = ws + OFF_A + 100000;
    float* Wsum  = ws + OFF_WSUM;
    float* bsum1 = ws + OFF_BSUM1;
    float* b2sum = ws + OFF_B2SUM;
    float* vvec  = ws + OFF_V;

    int* ee_cnt = wi + OFF_EE_CNT; int* ee_off = wi + OFF_EE_OFF; int* ee_csr = wi + OFF_EE_CSR;
    int* pe_cnt = wi + OFF_PE_CNT; int* pe_off = wi + OFF_PE_OFF; int* pe_csr = wi + OFF_PE_CSR;
    int* ep_cnt = wi + OFF_EP_CNT; int* ep_off = wi + OFF_EP_OFF; int* ep_csr = wi + OFF_EP_CSR;
    int* part   = wi + OFF_PART;

    dim3 blk128(16,16);  // M=128 GEMMs: BM=64
    dim3 blk64 (8,32);   // M=64  GEMMs: BM=128

    // ---- CSR build for all 3 relations ----
    hipMemsetAsync(ee_cnt, 0, 100000*sizeof(int), stream);
    hipMemsetAsync(pe_cnt, 0, 100000*sizeof(int), stream);
    hipMemsetAsync(ep_cnt, 0,  50000*sizeof(int), stream);

    prep_kernel<<<1,256,0,stream>>>(s1_ee_Wr, s1_pe_Wr, s1_ee_bl, s1_pe_bl,
                                    s2_pe_bl, gat_b, gat_Wdst, gat_adst,
                                    Wsum, bsum1, b2sum, vvec);

    count_int<<<ceil_div(NEE,256),256,0,stream>>>(ee_dst, ee_cnt, NEE);
    count_int<<<ceil_div(NPE,256),256,0,stream>>>(pe_dst, pe_cnt, NPE);
    count_int<<<ceil_div(NEP,256),256,0,stream>>>(ep_dst, ep_cnt, NEP);

    {   // ee scan
        int nb = ceil_div(NE_N,1024);
        scan_block<<<nb,256,0,stream>>>(ee_cnt, ee_off, part, NE_N);
        scan_partial<<<1,64,0,stream>>>(part, nb);
        add_base<<<ceil_div(NE_N+1,256),256,0,stream>>>(ee_off, part, NE_N, NEE);
        fill_csr<<<ceil_div(NEE,256),256,0,stream>>>(ee_src, ee_dst, ee_off, ee_cnt, ee_csr, NEE);
    }
    {   // pe scan
        int nb = ceil_div(NE_N,1024);
        scan_block<<<nb,256,0,stream>>>(pe_cnt, pe_off, part, NE_N);
        scan_partial<<<1,64,0,stream>>>(part, nb);
        add_base<<<ceil_div(NE_N+1,256),256,0,stream>>>(pe_off, part, NE_N, NPE);
        fill_csr<<<ceil_div(NPE,256),256,0,stream>>>(pe_src, pe_dst, pe_off, pe_cnt, pe_csr, NPE);
    }
    {   // ep scan
        int nb = ceil_div(NPER_N,1024);
        scan_block<<<nb,256,0,stream>>>(ep_cnt, ep_off, part, NPER_N);
        scan_partial<<<1,64,0,stream>>>(part, nb);
        add_base<<<ceil_div(NPER_N+1,256),256,0,stream>>>(ep_off, part, NPER_N, NEP);
        fill_csr<<<ceil_div(NEP,256),256,0,stream>>>(ep_src, ep_dst, ep_off, ep_cnt, ep_csr, NEP);
    }

    // ---- input projections ----
    gemm_kernel<64,128,16,true,true><<<ceil_div(NE_N,64),blk128,0,stream>>>(x_emp, lin_emp_w, lin_emp_b, h_emp, NE_N);
    gemm_kernel<32,128,16,true,true><<<ceil_div(NPER_N,64),blk128,0,stream>>>(x_per, lin_per_w, lin_per_b, h_per, NPER_N);

    // ---- conv1 ----
    gemm_kernel<128,128,16,false,true><<<ceil_div(NE_N,64),blk128,0,stream>>>(h_emp, Wsum, bsum1, emp1, NE_N);
    gemm_kernel<128,128,16,false,false><<<ceil_div(NE_N,64),blk128,0,stream>>>(h_emp, s1_ee_Wl, nullptr, proj_ee, NE_N);
    gemm_kernel<128,128,16,false,false><<<ceil_div(NPER_N,64),blk128,0,stream>>>(h_per, s1_pe_Wl, nullptr, proj_pe, NPER_N);
    agg_emp1<<<ceil_div((long long)NE_N*64,256),256,0,stream>>>(proj_ee, proj_pe, ee_off, ee_csr, pe_off, pe_csr, emp1);

    gemm_kernel<128,128,16,false,true><<<ceil_div(NPER_N,64),blk128,0,stream>>>(h_per, s1_ep_Wr, s1_ep_bl, per1, NPER_N);
    gemm_kernel<128,128,16,false,false><<<ceil_div(NE_N,64),blk128,0,stream>>>(h_emp, s1_ep_Wl, nullptr, proj_ee, NE_N); // proj_ep
    agg_per1<<<ceil_div((long long)NPER_N*64,256),256,0,stream>>>(proj_ee, ep_off, ep_csr, per1);

    // ---- conv2 prep (h_emp/h_per now dead) ----
    gemm_kernel<128,64,32,false,false><<<ceil_div(NE_N,128),blk64,0,stream>>>(emp1, gat_Wsrc, nullptr, zs, NE_N);
    rowdot64 <<<ceil_div(NE_N,4),256,0,stream>>>(zs,   gat_asrc, a_s, NE_N);
    rowdot128<<<ceil_div(NE_N,4),256,0,stream>>>(emp1, vvec,     a_d, NE_N);
    gemm_kernel<128,64,32,false,false><<<ceil_div(NPER_N,128),blk64,0,stream>>>(per1, s2_pe_Wl, nullptr, p2pe, NPER_N);
    gemm_kernel<128,64,32,false,false><<<ceil_div(NE_N,128),blk64,0,stream>>>(emp1, s2_ep_Wl, nullptr, p2ep, NE_N);

    // ---- conv2 outputs ----
    gemm_kernel<128,64,32,false,true><<<ceil_div(NE_N,128),blk64,0,stream>>>(emp1, s2_pe_Wr, b2sum, out_emp, NE_N);
    gat_sage_emp2<<<ceil_div((long long)NE_N*64,256),256,0,stream>>>(ee_off, ee_csr, pe_off, pe_csr, a_s, a_d, zs, p2pe, out_emp);

    gemm_kernel<128,64,32,false,true><<<ceil_div(NPER_N,128),blk64,0,stream>>>(per1, s2_ep_Wr, s2_ep_bl, out_per, NPER_N);
    agg_per2<<<ceil_div((long long)NPER_N*64,256),256,0,stream>>>(p2ep, ep_off, ep_csr, out_per);
}